// Round 1
// baseline (494.649 us; speedup 1.0000x reference)
//
#include <hip/hip_runtime.h>
#include <math.h>

#define CIN 128
#define HD  96
#define SP  3136   // 56*56
#define ROW 56

// ---------------- Kernel 1: q/value 1x1 conv (fused) ----------------
// out q[b][o][s] (o<96, Wc/bc) and v[b][o-96][s] (Wp/bp), s = flat 56*56.
// Grid: 64*49 blocks, 256 threads. S_TILE=64 contiguous, K_TILE=32.
__global__ __launch_bounds__(256) void qv_conv(
    const float* __restrict__ x, const float* __restrict__ Wc,
    const float* __restrict__ bc, const float* __restrict__ Wp,
    const float* __restrict__ bp, float* __restrict__ qbuf,
    float* __restrict__ vbuf)
{
  const int st = blockIdx.x % 49;
  const int b  = blockIdx.x / 49;
  const float* xb = x + (size_t)b * CIN * SP + st * 64;

  __shared__ float xs[32][64];     // 8 KB
  __shared__ float wl[32][196];    // 24.5 KB (pad 192->196: keeps 16B align, cuts write conflicts)

  const int tid = threadIdx.x;
  const int og = tid >> 4;       // 0..15 -> o0 = og*12
  const int sg = tid & 15;       // 0..15 -> s0 = sg*4

  float acc[12][4];
  #pragma unroll
  for (int i = 0; i < 12; ++i) { acc[i][0]=0.f; acc[i][1]=0.f; acc[i][2]=0.f; acc[i][3]=0.f; }

  for (int kt = 0; kt < 4; ++kt) {
    __syncthreads();
    // stage x tile [32][64]
    #pragma unroll
    for (int r = 0; r < 2; ++r) {
      int i = tid + r * 256;           // 0..511 float4 tasks
      int cc = i >> 4, s4 = i & 15;
      float4 v = *reinterpret_cast<const float4*>(xb + (size_t)(kt*32 + cc) * SP + s4*4);
      *reinterpret_cast<float4*>(&xs[cc][s4*4]) = v;
    }
    // stage W tile transposed: wl[cc][o], o in [0,192)
    #pragma unroll
    for (int r = 0; r < 6; ++r) {
      int i = tid + r * 256;           // 0..1535: 192 rows x 8 float4
      int o  = i >> 3, c4 = i & 7;
      const float* wrow = (o < 96) ? (Wc + (size_t)o * CIN) : (Wp + (size_t)(o - 96) * CIN);
      float4 wv = *reinterpret_cast<const float4*>(wrow + kt*32 + c4*4);
      wl[c4*4+0][o] = wv.x; wl[c4*4+1][o] = wv.y;
      wl[c4*4+2][o] = wv.z; wl[c4*4+3][o] = wv.w;
    }
    __syncthreads();
    #pragma unroll
    for (int cc = 0; cc < 32; ++cc) {
      float xv[4];
      *reinterpret_cast<float4*>(xv) = *reinterpret_cast<const float4*>(&xs[cc][sg*4]);
      float wv[12];
      *reinterpret_cast<float4*>(wv + 0) = *reinterpret_cast<const float4*>(&wl[cc][og*12 + 0]);
      *reinterpret_cast<float4*>(wv + 4) = *reinterpret_cast<const float4*>(&wl[cc][og*12 + 4]);
      *reinterpret_cast<float4*>(wv + 8) = *reinterpret_cast<const float4*>(&wl[cc][og*12 + 8]);
      #pragma unroll
      for (int i = 0; i < 12; ++i)
        #pragma unroll
        for (int j = 0; j < 4; ++j)
          acc[i][j] = fmaf(wv[i], xv[j], acc[i][j]);
    }
  }
  #pragma unroll
  for (int i = 0; i < 12; ++i) {
    int o = og * 12 + i;
    float bias; float* dst;
    if (o < 96) { bias = bc[o];      dst = qbuf + ((size_t)b*96 + o      ) * SP + st*64; }
    else        { bias = bp[o - 96]; dst = vbuf + ((size_t)b*96 + (o - 96)) * SP + st*64; }
    float4 v;
    v.x = acc[i][0] + bias; v.y = acc[i][1] + bias;
    v.z = acc[i][2] + bias; v.w = acc[i][3] + bias;
    *reinterpret_cast<float4*>(dst + sg*4) = v;
  }
}

// ---------------- Kernel 2: clustering, one block per folded batch b2 ----------------
// Reads q slice (qbuf) + v slice (vbuf), writes patches in-place over the q slice.
__global__ __launch_bounds__(256) void cluster_k(
    float* qbuf, const float* __restrict__ vbuf,
    const float* __restrict__ alpha_p, const float* __restrict__ beta_p)
{
  const int b2 = blockIdx.x;
  const int b  = b2 >> 4;
  const int e  = (b2 >> 2) & 3;
  const int f1 = (b2 >> 1) & 1;
  const int f2 = b2 & 1;
  const size_t base = ((size_t)b*96 + e*24) * SP + (size_t)(f1*28) * ROW + f2*28;
  float* qp = qbuf + base;
  const float* vp = vbuf + base;

  __shared__ double cn[4][24];     // normalized centers
  __shared__ double vc[4][24];     // value centers
  __shared__ double cl[4][24];     // cluster vectors
  __shared__ double dnm[4];
  __shared__ float sbest[784];
  __shared__ unsigned char ibest[784];

  const int tid = threadIdx.x;
  const double alpha = (double)alpha_p[0];
  const double beta  = (double)beta_p[0];

  // pass 0: adaptive-avg-pool centers (mean over 14x14 blocks)
  if (tid < 192) {
    const int which = (tid >= 96) ? 1 : 0;
    const int r = tid - which * 96;
    const int m = r / 24, c = r % 24;
    const int pw = m >> 1, ph = m & 1;
    const float* src = which ? vp : (const float*)qp;
    double s = 0.0;
    for (int w = pw*14; w < pw*14 + 14; ++w) {
      const float* row = src + (size_t)c * SP + (size_t)w * ROW + ph*14;
      for (int h = 0; h < 14; ++h) s += (double)row[h];
    }
    s *= (1.0 / 196.0);
    if (which) vc[m][c] = s; else cn[m][c] = s;
  }
  __syncthreads();
  // normalize centers
  if (tid < 4) {
    double s = 0.0;
    for (int c = 0; c < 24; ++c) s += cn[tid][c] * cn[tid][c];
    double nrm = sqrt(s);
    nrm = fmax(nrm, 1e-12);
    double inv = 1.0 / nrm;
    for (int c = 0; c < 24; ++c) cn[tid][c] *= inv;
  }
  __syncthreads();
  // pass A: per-pixel cosine sim -> sigmoid -> first-max argmax
  for (int n = tid; n < 784; n += 256) {
    const int w = n / 28, h = n % 28;
    const float* q0 = qp + (size_t)w * ROW + h;
    double qv[24];
    double nq = 0.0;
    #pragma unroll
    for (int c = 0; c < 24; ++c) { double t = (double)q0[(size_t)c * SP]; qv[c] = t; nq += t*t; }
    nq = sqrt(nq);
    nq = fmax(nq, 1e-12);
    const double inv = 1.0 / nq;
    double bests = -1.0; int bi = 0;
    #pragma unroll
    for (int m = 0; m < 4; ++m) {
      double d = 0.0;
      #pragma unroll
      for (int c = 0; c < 24; ++c) d += cn[m][c] * qv[c];
      double z = beta + alpha * (d * inv);
      double sgm = 1.0 / (1.0 + exp(-z));
      if (sgm > bests) { bests = sgm; bi = m; }   // strict > keeps first occurrence
    }
    sbest[n] = (float)bests;
    ibest[n] = (unsigned char)bi;
  }
  __syncthreads();
  // pass B: masked segment sums (deterministic sequential order)
  if (tid < 96) {
    const int m = tid / 24, c = tid % 24;
    const float* v0 = vp + (size_t)c * SP;
    double s = 0.0;
    int n = 0;
    for (int w = 0; w < 28; ++w)
      for (int h = 0; h < 28; ++h, ++n)
        if (ibest[n] == (unsigned char)m)
          s += (double)sbest[n] * (double)v0[w*ROW + h];
    cl[m][c] = s;
  }
  if (tid >= 128 && tid < 132) {
    const int m = tid - 128;
    double s = 0.0;
    for (int n = 0; n < 784; ++n)
      if (ibest[n] == (unsigned char)m) s += (double)sbest[n];
    dnm[m] = s;
  }
  __syncthreads();
  if (tid < 96) {
    const int m = tid / 24, c = tid % 24;
    cl[m][c] = (cl[m][c] + vc[m][c]) / (dnm[m] + 1.0);
  }
  __syncthreads();
  // pass C: patches = sim[argmax] * cluster[argmax], overwrite q slice
  for (int t = tid; t < 24 * 784; t += 256) {
    const int c = t / 784, n = t % 784;
    const int w = n / 28, h = n % 28;
    qp[(size_t)c * SP + (size_t)w * ROW + h] = sbest[n] * (float)cl[ibest[n]][c];
  }
}

// ---------------- Kernel 3: output 1x1 conv ----------------
__global__ __launch_bounds__(256) void out_conv(
    const float* __restrict__ pbuf, const float* __restrict__ Wo,
    const float* __restrict__ bo, float* __restrict__ out)
{
  const int st = blockIdx.x % 49;
  const int b  = blockIdx.x / 49;
  const float* pb = pbuf + (size_t)b * HD * SP + st * 64;

  __shared__ float xs[32][64];
  __shared__ float wl[32][132];   // pad 128->132

  const int tid = threadIdx.x;
  const int og = tid >> 4;        // 0..15 -> co0 = og*8
  const int sg = tid & 15;        // 0..15 -> s0 = sg*4

  float acc[8][4];
  #pragma unroll
  for (int i = 0; i < 8; ++i) { acc[i][0]=0.f; acc[i][1]=0.f; acc[i][2]=0.f; acc[i][3]=0.f; }

  for (int kt = 0; kt < 3; ++kt) {
    __syncthreads();
    #pragma unroll
    for (int r = 0; r < 2; ++r) {
      int i = tid + r * 256;
      int cc = i >> 4, s4 = i & 15;
      float4 v = *reinterpret_cast<const float4*>(pb + (size_t)(kt*32 + cc) * SP + s4*4);
      *reinterpret_cast<float4*>(&xs[cc][s4*4]) = v;
    }
    #pragma unroll
    for (int r = 0; r < 4; ++r) {
      int i = tid + r * 256;          // 0..1023: 128 rows x 8 float4
      int co = i >> 3, c4 = i & 7;
      float4 wv = *reinterpret_cast<const float4*>(Wo + (size_t)co * HD + kt*32 + c4*4);
      wl[c4*4+0][co] = wv.x; wl[c4*4+1][co] = wv.y;
      wl[c4*4+2][co] = wv.z; wl[c4*4+3][co] = wv.w;
    }
    __syncthreads();
    #pragma unroll
    for (int cc = 0; cc < 32; ++cc) {
      float xv[4];
      *reinterpret_cast<float4*>(xv) = *reinterpret_cast<const float4*>(&xs[cc][sg*4]);
      float wv[8];
      *reinterpret_cast<float4*>(wv + 0) = *reinterpret_cast<const float4*>(&wl[cc][og*8 + 0]);
      *reinterpret_cast<float4*>(wv + 4) = *reinterpret_cast<const float4*>(&wl[cc][og*8 + 4]);
      #pragma unroll
      for (int i = 0; i < 8; ++i)
        #pragma unroll
        for (int j = 0; j < 4; ++j)
          acc[i][j] = fmaf(wv[i], xv[j], acc[i][j]);
    }
  }
  #pragma unroll
  for (int i = 0; i < 8; ++i) {
    int co = og * 8 + i;
    float bias = bo[co];
    float4 v;
    v.x = acc[i][0] + bias; v.y = acc[i][1] + bias;
    v.z = acc[i][2] + bias; v.w = acc[i][3] + bias;
    *reinterpret_cast<float4*>(out + ((size_t)b*128 + co) * SP + st*64 + sg*4) = v;
  }
}

extern "C" void kernel_launch(void* const* d_in, const int* in_sizes, int n_in,
                              void* d_out, int out_size, void* d_ws, size_t ws_size,
                              hipStream_t stream) {
  const float* x  = (const float*)d_in[0];
  const float* Wc = (const float*)d_in[1];
  const float* bc = (const float*)d_in[2];
  const float* Wp = (const float*)d_in[3];
  const float* bp = (const float*)d_in[4];
  const float* sa = (const float*)d_in[5];
  const float* sb = (const float*)d_in[6];
  const float* Wo = (const float*)d_in[7];
  const float* bo = (const float*)d_in[8];
  float* out  = (float*)d_out;
  float* qbuf = (float*)d_ws;   // 64*96*3136 fp32 = 77.1 MB (patches written in-place)
  float* vbuf = out;            // value scratch inside d_out; fully overwritten by out_conv

  dim3 blk(256);
  qv_conv<<<dim3(64 * 49), blk, 0, stream>>>(x, Wc, bc, Wp, bp, qbuf, vbuf);
  cluster_k<<<dim3(1024), blk, 0, stream>>>(qbuf, vbuf, sa, sb);
  out_conv<<<dim3(64 * 49), blk, 0, stream>>>(qbuf, Wo, bo, out);
}

// Round 2
// 486.343 us; speedup vs baseline: 1.0171x; 1.0171x over previous
//
#include <hip/hip_runtime.h>
#include <math.h>

#define CIN 128
#define HD  96
#define SP  3136   // 56*56
#define ROW 56

// ---------------- Kernel 1: q/value 1x1 conv (fused) ----------------
__global__ __launch_bounds__(256) void qv_conv(
    const float* __restrict__ x, const float* __restrict__ Wc,
    const float* __restrict__ bc, const float* __restrict__ Wp,
    const float* __restrict__ bp, float* __restrict__ qbuf,
    float* __restrict__ vbuf)
{
  const int st = blockIdx.x % 49;
  const int b  = blockIdx.x / 49;
  const float* xb = x + (size_t)b * CIN * SP + st * 64;

  __shared__ float xs[32][64];
  __shared__ float wl[32][196];

  const int tid = threadIdx.x;
  const int og = tid >> 4;
  const int sg = tid & 15;

  float acc[12][4];
  #pragma unroll
  for (int i = 0; i < 12; ++i) { acc[i][0]=0.f; acc[i][1]=0.f; acc[i][2]=0.f; acc[i][3]=0.f; }

  for (int kt = 0; kt < 4; ++kt) {
    __syncthreads();
    #pragma unroll
    for (int r = 0; r < 2; ++r) {
      int i = tid + r * 256;
      int cc = i >> 4, s4 = i & 15;
      float4 v = *reinterpret_cast<const float4*>(xb + (size_t)(kt*32 + cc) * SP + s4*4);
      *reinterpret_cast<float4*>(&xs[cc][s4*4]) = v;
    }
    #pragma unroll
    for (int r = 0; r < 6; ++r) {
      int i = tid + r * 256;
      int o  = i >> 3, c4 = i & 7;
      const float* wrow = (o < 96) ? (Wc + (size_t)o * CIN) : (Wp + (size_t)(o - 96) * CIN);
      float4 wv = *reinterpret_cast<const float4*>(wrow + kt*32 + c4*4);
      wl[c4*4+0][o] = wv.x; wl[c4*4+1][o] = wv.y;
      wl[c4*4+2][o] = wv.z; wl[c4*4+3][o] = wv.w;
    }
    __syncthreads();
    #pragma unroll
    for (int cc = 0; cc < 32; ++cc) {
      float xv[4];
      *reinterpret_cast<float4*>(xv) = *reinterpret_cast<const float4*>(&xs[cc][sg*4]);
      float wv[12];
      *reinterpret_cast<float4*>(wv + 0) = *reinterpret_cast<const float4*>(&wl[cc][og*12 + 0]);
      *reinterpret_cast<float4*>(wv + 4) = *reinterpret_cast<const float4*>(&wl[cc][og*12 + 4]);
      *reinterpret_cast<float4*>(wv + 8) = *reinterpret_cast<const float4*>(&wl[cc][og*12 + 8]);
      #pragma unroll
      for (int i = 0; i < 12; ++i)
        #pragma unroll
        for (int j = 0; j < 4; ++j)
          acc[i][j] = fmaf(wv[i], xv[j], acc[i][j]);
    }
  }
  #pragma unroll
  for (int i = 0; i < 12; ++i) {
    int o = og * 12 + i;
    float bias; float* dst;
    if (o < 96) { bias = bc[o];      dst = qbuf + ((size_t)b*96 + o      ) * SP + st*64; }
    else        { bias = bp[o - 96]; dst = vbuf + ((size_t)b*96 + (o - 96)) * SP + st*64; }
    float4 v;
    v.x = acc[i][0] + bias; v.y = acc[i][1] + bias;
    v.z = acc[i][2] + bias; v.w = acc[i][3] + bias;
    *reinterpret_cast<float4*>(dst + sg*4) = v;
  }
}

// ---------------- Kernel 2: clustering, one 768-thread block per folded batch ----------------
__global__ __launch_bounds__(768) void cluster_k(
    float* qbuf, const float* __restrict__ vbuf,
    const float* __restrict__ alpha_p, const float* __restrict__ beta_p)
{
  const int b2 = blockIdx.x;
  const int b  = b2 >> 4;
  const int e  = (b2 >> 2) & 3;
  const int f1 = (b2 >> 1) & 1;
  const int f2 = b2 & 1;
  const size_t base = ((size_t)b*96 + e*24) * SP + (size_t)(f1*28) * ROW + f2*28;
  float* qp = qbuf + base;
  const float* vp = vbuf + base;

  __shared__ double cnd[4][24];       // pooled, then normalized q centers
  __shared__ float  sbest[784];
  __shared__ short  ibest[784];
  __shared__ float  clr[4][24];       // masked segment sums
  __shared__ float  vcf[4][24];       // pooled value centers
  __shared__ float  clf[4][28];       // final cluster vectors (padded)
  __shared__ float  dnf[4];

  const int tid = threadIdx.x;

  // ---- pass 0: adaptive-pool q centers (8 threads per (m,c), shuffle combine) ----
  {
    const int pair = tid >> 3;        // 0..95
    const int j    = tid & 7;
    const int m = pair / 24, c = pair % 24;
    const int pw = m >> 1, ph = m & 1;
    const float* src = qp + (size_t)c * SP + (size_t)(pw*14) * ROW + ph*14;
    double s = 0.0;
    for (int k = j; k < 196; k += 8) {
      int w = k / 14, h = k % 14;
      s += (double)src[w * ROW + h];
    }
    s += __shfl_xor(s, 1);
    s += __shfl_xor(s, 2);
    s += __shfl_xor(s, 4);
    if (j == 0) cnd[m][c] = s * (1.0/196.0);
  }
  __syncthreads();
  if (tid < 4) {
    double s = 0.0;
    #pragma unroll
    for (int c = 0; c < 24; ++c) s += cnd[tid][c] * cnd[tid][c];
    double inv = 1.0 / fmax(sqrt(s), 1e-12);
    #pragma unroll
    for (int c = 0; c < 24; ++c) cnd[tid][c] *= inv;
  }
  __syncthreads();

  const double alpha = (double)alpha_p[0];
  const double beta  = (double)beta_p[0];

  // ---- pass A: per-pixel z (fp64 dots), first-max argmax, one sigmoid ----
  for (int n = tid; n < 784; n += 768) {
    const int w = n / 28, h = n % 28;
    const float* q0 = qp + (size_t)w * ROW + h;
    float qv[24];
    double nq = 0.0;
    #pragma unroll
    for (int c = 0; c < 24; ++c) {
      float t = q0[(size_t)c * SP];
      qv[c] = t;
      nq += (double)t * (double)t;
    }
    const double inv = 1.0 / fmax(sqrt(nq), 1e-12);
    double zb = -1.0e300; int bi = 0;
    #pragma unroll
    for (int m = 0; m < 4; ++m) {
      double d = 0.0;
      #pragma unroll
      for (int c = 0; c < 24; ++c) d += cnd[m][c] * (double)qv[c];
      double z = beta + alpha * (d * inv);
      if (z > zb) { zb = z; bi = m; }    // strict > keeps first occurrence (sigmoid monotone)
    }
    sbest[n] = (float)(1.0 / (1.0 + exp(-zb)));
    ibest[n] = (short)bi;
  }
  __syncthreads();

  // ---- pass B: 32 lanes per channel; masked sums + v-pooling fused (v read ONCE) ----
  {
    const int c = tid >> 5;            // 0..23
    const int j = tid & 31;
    const float* v0 = vp + (size_t)c * SP;
    float cl0=0.f,cl1=0.f,cl2=0.f,cl3=0.f;
    float vc0=0.f,vc1=0.f,vc2=0.f,vc3=0.f;
    float dn0=0.f,dn1=0.f,dn2=0.f,dn3=0.f;
    for (int n = j; n < 784; n += 32) {
      const int w = n / 28, h = n % 28;
      const float v = v0[w * ROW + h];
      const float s = sbest[n];
      const int  ib = ibest[n];
      const float sv = s * v;
      cl0 += (ib==0) ? sv : 0.f;  cl1 += (ib==1) ? sv : 0.f;
      cl2 += (ib==2) ? sv : 0.f;  cl3 += (ib==3) ? sv : 0.f;
      const int mp = ((w >= 14) ? 2 : 0) + ((h >= 14) ? 1 : 0);
      vc0 += (mp==0) ? v : 0.f;   vc1 += (mp==1) ? v : 0.f;
      vc2 += (mp==2) ? v : 0.f;   vc3 += (mp==3) ? v : 0.f;
      dn0 += (ib==0) ? s : 0.f;   dn1 += (ib==1) ? s : 0.f;
      dn2 += (ib==2) ? s : 0.f;   dn3 += (ib==3) ? s : 0.f;
    }
    #pragma unroll
    for (int msk = 16; msk >= 1; msk >>= 1) {
      cl0 += __shfl_xor(cl0, msk); cl1 += __shfl_xor(cl1, msk);
      cl2 += __shfl_xor(cl2, msk); cl3 += __shfl_xor(cl3, msk);
      vc0 += __shfl_xor(vc0, msk); vc1 += __shfl_xor(vc1, msk);
      vc2 += __shfl_xor(vc2, msk); vc3 += __shfl_xor(vc3, msk);
      dn0 += __shfl_xor(dn0, msk); dn1 += __shfl_xor(dn1, msk);
      dn2 += __shfl_xor(dn2, msk); dn3 += __shfl_xor(dn3, msk);
    }
    if (j == 0) {
      clr[0][c]=cl0; clr[1][c]=cl1; clr[2][c]=cl2; clr[3][c]=cl3;
      vcf[0][c]=vc0*(1.f/196.f); vcf[1][c]=vc1*(1.f/196.f);
      vcf[2][c]=vc2*(1.f/196.f); vcf[3][c]=vc3*(1.f/196.f);
      if (c == 0) { dnf[0]=dn0; dnf[1]=dn1; dnf[2]=dn2; dnf[3]=dn3; }
    }
  }
  __syncthreads();
  if (tid < 96) {
    const int m = tid / 24, c = tid % 24;
    clf[m][c] = (clr[m][c] + vcf[m][c]) / (dnf[m] + 1.0f);
  }
  __syncthreads();

  // ---- pass C: patches = sbest * cluster[ibest], overwrite q slice ----
  for (int t = tid; t < 24 * 784; t += 768) {
    const int c = t / 784, n = t % 784;
    const int w = n / 28, h = n % 28;
    qp[(size_t)c * SP + (size_t)w * ROW + h] = sbest[n] * clf[ibest[n]][c];
  }
}

// ---------------- Kernel 3: output 1x1 conv ----------------
__global__ __launch_bounds__(256) void out_conv(
    const float* __restrict__ pbuf, const float* __restrict__ Wo,
    const float* __restrict__ bo, float* __restrict__ out)
{
  const int st = blockIdx.x % 49;
  const int b  = blockIdx.x / 49;
  const float* pb = pbuf + (size_t)b * HD * SP + st * 64;

  __shared__ float xs[32][64];
  __shared__ float wl[32][132];

  const int tid = threadIdx.x;
  const int og = tid >> 4;
  const int sg = tid & 15;

  float acc[8][4];
  #pragma unroll
  for (int i = 0; i < 8; ++i) { acc[i][0]=0.f; acc[i][1]=0.f; acc[i][2]=0.f; acc[i][3]=0.f; }

  for (int kt = 0; kt < 3; ++kt) {
    __syncthreads();
    #pragma unroll
    for (int r = 0; r < 2; ++r) {
      int i = tid + r * 256;
      int cc = i >> 4, s4 = i & 15;
      float4 v = *reinterpret_cast<const float4*>(pb + (size_t)(kt*32 + cc) * SP + s4*4);
      *reinterpret_cast<float4*>(&xs[cc][s4*4]) = v;
    }
    #pragma unroll
    for (int r = 0; r < 4; ++r) {
      int i = tid + r * 256;
      int co = i >> 3, c4 = i & 7;
      float4 wv = *reinterpret_cast<const float4*>(Wo + (size_t)co * HD + kt*32 + c4*4);
      wl[c4*4+0][co] = wv.x; wl[c4*4+1][co] = wv.y;
      wl[c4*4+2][co] = wv.z; wl[c4*4+3][co] = wv.w;
    }
    __syncthreads();
    #pragma unroll
    for (int cc = 0; cc < 32; ++cc) {
      float xv[4];
      *reinterpret_cast<float4*>(xv) = *reinterpret_cast<const float4*>(&xs[cc][sg*4]);
      float wv[8];
      *reinterpret_cast<float4*>(wv + 0) = *reinterpret_cast<const float4*>(&wl[cc][og*8 + 0]);
      *reinterpret_cast<float4*>(wv + 4) = *reinterpret_cast<const float4*>(&wl[cc][og*8 + 4]);
      #pragma unroll
      for (int i = 0; i < 8; ++i)
        #pragma unroll
        for (int j = 0; j < 4; ++j)
          acc[i][j] = fmaf(wv[i], xv[j], acc[i][j]);
    }
  }
  #pragma unroll
  for (int i = 0; i < 8; ++i) {
    int co = og * 8 + i;
    float bias = bo[co];
    float4 v;
    v.x = acc[i][0] + bias; v.y = acc[i][1] + bias;
    v.z = acc[i][2] + bias; v.w = acc[i][3] + bias;
    *reinterpret_cast<float4*>(out + ((size_t)b*128 + co) * SP + st*64 + sg*4) = v;
  }
}

extern "C" void kernel_launch(void* const* d_in, const int* in_sizes, int n_in,
                              void* d_out, int out_size, void* d_ws, size_t ws_size,
                              hipStream_t stream) {
  const float* x  = (const float*)d_in[0];
  const float* Wc = (const float*)d_in[1];
  const float* bc = (const float*)d_in[2];
  const float* Wp = (const float*)d_in[3];
  const float* bp = (const float*)d_in[4];
  const float* sa = (const float*)d_in[5];
  const float* sb = (const float*)d_in[6];
  const float* Wo = (const float*)d_in[7];
  const float* bo = (const float*)d_in[8];
  float* out  = (float*)d_out;
  float* qbuf = (float*)d_ws;   // 77.1 MB; patches overwrite in-place
  float* vbuf = out;            // value scratch inside d_out; fully overwritten by out_conv

  qv_conv<<<dim3(64 * 49), dim3(256), 0, stream>>>(x, Wc, bc, Wp, bp, qbuf, vbuf);
  cluster_k<<<dim3(1024), dim3(768), 0, stream>>>(qbuf, vbuf, sa, sb);
  out_conv<<<dim3(64 * 49), dim3(256), 0, stream>>>(qbuf, Wo, bo, out);
}